// Round 5
// baseline (163.450 us; speedup 1.0000x reference)
//
#include <hip/hip_runtime.h>

// Problem: B=2, N=2048, D=1024, H=16, hd=64, WINDOW=256 (causal + local window)
// Inputs FLOAT32, output FLOAT32; internal compute bf16 MFMA.
//
// R17: 2-phase double-buffered pipeline (T3-minimum + T4 counted vmcnt) on
// BOTH GEMMs. R16 counters showed QKV latency-bound (MfmaUtil 23%, VALU 18%,
// HBM 16%, nothing saturated): the old stage->drain->compute loop serialized
// global->LDS latency into every K-iter. Now: issue next tile's 6
// global_load_lds into buf^1 BEFORE computing buf, wait s_waitcnt vmcnt(6)
// (counted, not 0), barrier, compute, barrier. LDS 48KB/block (3 blocks/CU).
// Attn + prep unchanged from R16 (V stored pre-transposed by QKV).

typedef unsigned short ushort_t;
typedef __bf16 bf16x8 __attribute__((ext_vector_type(8)));
typedef float f32x4 __attribute__((ext_vector_type(4)));
typedef unsigned short ushort8 __attribute__((ext_vector_type(8)));
typedef unsigned short ushort4v __attribute__((ext_vector_type(4)));

#define LOG2E 1.4426950408889634f

static __device__ __forceinline__ ushort_t f2b(float f) {
    union { float f; unsigned int u; } x;
    x.f = f;
    unsigned int u = x.u;
    unsigned int r = (u + 0x7FFFu + ((u >> 16) & 1u)) >> 16;
    return (ushort_t)r;
}

static __device__ __forceinline__ void store_out(float* p, float v) { *p = v; }
static __device__ __forceinline__ void store_out(ushort_t* p, float v) { *p = f2b(v); }

// swizzled element offset of 8-elem chunk c of row `row` (8 chunks/row)
static __device__ __forceinline__ int sw(int row, int c) {
    return (row * 8 + (c ^ (row & 7))) * 8;
}

// async global->LDS 16B copy: per-lane lds addr = wave-base + lane*16
static __device__ __forceinline__ void gload_lds16(const ushort_t* g, ushort_t* l) {
    __builtin_amdgcn_global_load_lds(
        (const __attribute__((address_space(1))) void*)g,
        (__attribute__((address_space(3))) void*)l, 16, 0, 0);
}

// ---------------------------------------------------------------------------
// 0+1) prep: z<4 -> 1024x1024 transpose+cast of W[z]; z==4 -> x cast (16/thr)
// ---------------------------------------------------------------------------
__global__ __launch_bounds__(256) void prep_kernel(
    const float* __restrict__ x, ushort_t* __restrict__ xbf,
    const float* __restrict__ W0, const float* __restrict__ W1,
    const float* __restrict__ W2, const float* __restrict__ W3,
    ushort_t* __restrict__ T0, ushort_t* __restrict__ T1,
    ushort_t* __restrict__ T2, ushort_t* __restrict__ T3) {
    int tx = threadIdx.x, ty = threadIdx.y;  // block (32,8)
    if (blockIdx.z == 4) {
        // x cast: 1024 blocks x 256 threads x 16 elems = 4,194,304
        int idx = (blockIdx.y * 32 + blockIdx.x) * 256 + ty * 32 + tx;
        int i = idx * 16;
#pragma unroll
        for (int half = 0; half < 2; half++) {
            f32x4 a = *(const f32x4*)&x[i + half * 8];
            f32x4 b = *(const f32x4*)&x[i + half * 8 + 4];
            ushort8 o;
#pragma unroll
            for (int e = 0; e < 4; e++) o[e] = f2b(a[e]);
#pragma unroll
            for (int e = 0; e < 4; e++) o[4 + e] = f2b(b[e]);
            *(ushort8*)&xbf[i + half * 8] = o;
        }
        return;
    }
    __shared__ ushort_t tile[32][33];
    const float* W;
    ushort_t* T;
    switch (blockIdx.z) {
        case 0: W = W0; T = T0; break;
        case 1: W = W1; T = T1; break;
        case 2: W = W2; T = T2; break;
        default: W = W3; T = T3; break;
    }
    int xx = blockIdx.x * 32 + tx;
    int ybase = blockIdx.y * 32 + ty;
#pragma unroll
    for (int r = 0; r < 4; r++) tile[ty + r * 8][tx] = f2b(W[(ybase + r * 8) * 1024 + xx]);
    __syncthreads();
    int xo = blockIdx.y * 32 + tx;
    int yobase = blockIdx.x * 32 + ty;
#pragma unroll
    for (int r = 0; r < 4; r++) T[(yobase + r * 8) * 1024 + xo] = tile[tx][ty + r * 8];
}

// ---------------------------------------------------------------------------
// 2) QKV GEMM: C[M,1024] = (A @ Bt^T + bias) * oscale, 64x128 tile, 4 waves.
// 2-phase dbuf pipeline, counted vmcnt(6), XOR-swizzled gload_lds staging,
// XCD swizzle, staggered K. 1536 blocks. zsel==2 (V) stores transposed.
// ---------------------------------------------------------------------------
__global__ __launch_bounds__(256) void gemm_qkv_kernel(
    const ushort_t* __restrict__ A,
    const ushort_t* __restrict__ Bt0, const ushort_t* __restrict__ Bt1,
    const ushort_t* __restrict__ Bt2,
    const float* __restrict__ bias0, const float* __restrict__ bias1,
    const float* __restrict__ bias2,
    ushort_t* __restrict__ C0, ushort_t* __restrict__ C1, ushort_t* __restrict__ C2,
    float os0, float os1, float os2) {
    __shared__ ushort_t Al[2][64 * 64];    // 16 KB
    __shared__ ushort_t Bl[2][128 * 64];   // 32 KB

    const int id = blockIdx.x;
    const int xcd = id & 7;
    const int s = id >> 3;
    int m_blk = (xcd >> 1) * 16 + (s & 15);       // 0..63
    int ncol = (xcd & 1) * 12 + (s >> 4);         // 0..23 fused (z,x)
    int zsel = ncol >> 3;
    ncol &= 7;
    const int m0 = m_blk * 64;
    const int n0 = ncol * 128;

    const ushort_t* Bt;
    const float* bias;
    ushort_t* C;
    float oscale;
    if (zsel == 0) { Bt = Bt0; bias = bias0; C = C0; oscale = os0; }
    else if (zsel == 1) { Bt = Bt1; bias = bias1; C = C1; oscale = os1; }
    else { Bt = Bt2; bias = bias2; C = C2; oscale = os2; }

    const int tid = threadIdx.x;
    const int w = tid >> 6;
    const int l = tid & 63;
    const int wm = (w >> 1) * 32;
    const int wn = (w & 1) * 64;
    const int lrow = l & 15;
    const int lq = l >> 4;

    f32x4 acc[2][4];
#pragma unroll
    for (int mi = 0; mi < 2; mi++)
#pragma unroll
        for (int ni = 0; ni < 4; ni++) acc[mi][ni] = 0.0f;

    const int kt0 = (id * 5) & 15;

    // stage tile `itv` (mod 16) into buffer `bsel`: 6 gload_lds16 per thread
    auto stage = [&](int bsel, int itv) {
        const int kt = ((kt0 + itv) & 15) * 64;
#pragma unroll
        for (int t = 0; t < 2; t++) {
            int idx = t * 256 + tid;
            int row = idx >> 3, cc = idx & 7, c = cc ^ (row & 7);
            gload_lds16(&A[(long)(m0 + row) * 1024 + kt + c * 8], &Al[bsel][idx * 8]);
        }
#pragma unroll
        for (int t = 0; t < 4; t++) {
            int idx = t * 256 + tid;
            int row = idx >> 3, cc = idx & 7, c = cc ^ (row & 7);
            gload_lds16(&Bt[(long)(n0 + row) * 1024 + kt + c * 8], &Bl[bsel][idx * 8]);
        }
    };

    stage(0, 0);           // prologue: 6 loads in flight
    int cur = 0;
    for (int it = 0; it < 16; it++) {
        stage(cur ^ 1, it + 1);  // it=15 stages a junk tile: keeps vmcnt math uniform
        asm volatile("s_waitcnt vmcnt(6)" ::: "memory");  // prev tile's 6 landed (per wave)
        __builtin_amdgcn_s_barrier();                      // all waves' portions landed
        asm volatile("" ::: "memory");
        __builtin_amdgcn_sched_barrier(0);
        const ushort_t* Ac = Al[cur];
        const ushort_t* Bc = Bl[cur];
#pragma unroll
        for (int ks = 0; ks < 64; ks += 32) {
            const int cb = (ks >> 3) + lq;
            bf16x8 af[2], bfr[4];
#pragma unroll
            for (int mi = 0; mi < 2; mi++)
                af[mi] = *(const bf16x8*)&Ac[sw(wm + mi * 16 + lrow, cb)];
#pragma unroll
            for (int ni = 0; ni < 4; ni++)
                bfr[ni] = *(const bf16x8*)&Bc[sw(wn + ni * 16 + lrow, cb)];
#pragma unroll
            for (int mi = 0; mi < 2; mi++)
#pragma unroll
                for (int ni = 0; ni < 4; ni++)
                    acc[mi][ni] = __builtin_amdgcn_mfma_f32_16x16x32_bf16(
                        af[mi], bfr[ni], acc[mi][ni], 0, 0, 0);
        }
        __builtin_amdgcn_sched_barrier(0);
        asm volatile("" ::: "memory");
        __builtin_amdgcn_s_barrier();                      // buf[cur] free for overwrite
        cur ^= 1;
    }
    asm volatile("s_waitcnt vmcnt(0)" ::: "memory");       // drain junk LDS-DMA pre-exit

    if (zsel == 2) {
        // V: transposed store VT[n][m], 4 consecutive m packed per lane (8B)
#pragma unroll
        for (int ni = 0; ni < 4; ni++) {
            int n = n0 + wn + ni * 16 + lrow;
            float bv = bias[n];
#pragma unroll
            for (int mi = 0; mi < 2; mi++) {
                int m = m0 + wm + mi * 16 + lq * 4;
                ushort4v o;
#pragma unroll
                for (int r = 0; r < 4; r++) o[r] = f2b((acc[mi][ni][r] + bv) * oscale);
                *(ushort4v*)&C[(long)n * 4096 + m] = o;
            }
        }
    } else {
#pragma unroll
        for (int ni = 0; ni < 4; ni++) {
            int n = n0 + wn + ni * 16 + lrow;
            float bv = bias[n];
#pragma unroll
            for (int mi = 0; mi < 2; mi++) {
#pragma unroll
                for (int r = 0; r < 4; r++) {
                    int m = m0 + wm + mi * 16 + lq * 4 + r;
                    store_out(&C[(long)m * 1024 + n], (acc[mi][ni][r] + bv) * oscale);
                }
            }
        }
    }
}

// ---------------------------------------------------------------------------
// 4) Out-proj GEMM: out[M,1024] = attO @ Wo^T + bo (fp32 out). 64x128 tile,
// same 2-phase dbuf counted-vmcnt pipeline. 512 blocks.
// ---------------------------------------------------------------------------
__global__ __launch_bounds__(256) void gemm_out_kernel(
    const ushort_t* __restrict__ A, const ushort_t* __restrict__ Bt,
    const float* __restrict__ bias, float* __restrict__ C) {
    __shared__ ushort_t Al[2][64 * 64];
    __shared__ ushort_t Bl[2][128 * 64];

    const int id = blockIdx.x;
    const int xcd = id & 7;
    const int s = id >> 3;
    const int m_blk = xcd * 8 + (s & 7);          // 0..63
    const int ncol = s >> 3;                      // 0..7
    const int m0 = m_blk * 64;
    const int n0 = ncol * 128;

    const int tid = threadIdx.x;
    const int w = tid >> 6;
    const int l = tid & 63;
    const int wm = (w >> 1) * 32;
    const int wn = (w & 1) * 64;
    const int lrow = l & 15;
    const int lq = l >> 4;

    f32x4 acc[2][4];
#pragma unroll
    for (int mi = 0; mi < 2; mi++)
#pragma unroll
        for (int ni = 0; ni < 4; ni++) acc[mi][ni] = 0.0f;

    const int kt0 = (id * 5) & 15;

    auto stage = [&](int bsel, int itv) {
        const int kt = ((kt0 + itv) & 15) * 64;
#pragma unroll
        for (int t = 0; t < 2; t++) {
            int idx = t * 256 + tid;
            int row = idx >> 3, cc = idx & 7, c = cc ^ (row & 7);
            gload_lds16(&A[(long)(m0 + row) * 1024 + kt + c * 8], &Al[bsel][idx * 8]);
        }
#pragma unroll
        for (int t = 0; t < 4; t++) {
            int idx = t * 256 + tid;
            int row = idx >> 3, cc = idx & 7, c = cc ^ (row & 7);
            gload_lds16(&Bt[(long)(n0 + row) * 1024 + kt + c * 8], &Bl[bsel][idx * 8]);
        }
    };

    stage(0, 0);
    int cur = 0;
    for (int it = 0; it < 16; it++) {
        stage(cur ^ 1, it + 1);
        asm volatile("s_waitcnt vmcnt(6)" ::: "memory");
        __builtin_amdgcn_s_barrier();
        asm volatile("" ::: "memory");
        __builtin_amdgcn_sched_barrier(0);
        const ushort_t* Ac = Al[cur];
        const ushort_t* Bc = Bl[cur];
#pragma unroll
        for (int ks = 0; ks < 64; ks += 32) {
            const int cb = (ks >> 3) + lq;
            bf16x8 af[2], bfr[4];
#pragma unroll
            for (int mi = 0; mi < 2; mi++)
                af[mi] = *(const bf16x8*)&Ac[sw(wm + mi * 16 + lrow, cb)];
#pragma unroll
            for (int ni = 0; ni < 4; ni++)
                bfr[ni] = *(const bf16x8*)&Bc[sw(wn + ni * 16 + lrow, cb)];
#pragma unroll
            for (int mi = 0; mi < 2; mi++)
#pragma unroll
                for (int ni = 0; ni < 4; ni++)
                    acc[mi][ni] = __builtin_amdgcn_mfma_f32_16x16x32_bf16(
                        af[mi], bfr[ni], acc[mi][ni], 0, 0, 0);
        }
        __builtin_amdgcn_sched_barrier(0);
        asm volatile("" ::: "memory");
        __builtin_amdgcn_s_barrier();
        cur ^= 1;
    }
    asm volatile("s_waitcnt vmcnt(0)" ::: "memory");

#pragma unroll
    for (int ni = 0; ni < 4; ni++) {
        int n = n0 + wn + ni * 16 + lrow;
        float bv = bias[n];
#pragma unroll
        for (int mi = 0; mi < 2; mi++) {
#pragma unroll
            for (int r = 0; r < 4; r++) {
                int m = m0 + wm + mi * 16 + lq * 4 + r;
                C[(long)m * 1024 + n] = acc[mi][ni][r] + bv;
            }
        }
    }
}

// ---------------------------------------------------------------------------
// 3) Flash attention, window=256 causal. 1024 blocks, XCD-swizzled. K tile
// AND V^T tile both staged via swizzled async gload_lds16 (no software
// transpose). VT input is [feature][token]. Fixed-max softmax, deferred
// row-sum, P round-trip via per-wave LDS buffer.
// ---------------------------------------------------------------------------
__global__ __launch_bounds__(256) void attn_kernel(
    const ushort_t* __restrict__ Q, const ushort_t* __restrict__ K,
    const ushort_t* __restrict__ VT, ushort_t* __restrict__ O) {
    __shared__ ushort_t Kl[128 * 64];    // K chunk, swizzled [key][d]     16 KB
    __shared__ ushort_t Vtl[64 * 128];   // V^T chunk, swizzled [d][key]   16 KB
    __shared__ ushort_t Pb[4 * 16 * 40]; // per-wave P buffer [16 q][32 key]

    const int id = blockIdx.x;
    const int xcd = id & 7;
    const int s = id >> 3;               // 0..127
    const int bh = xcd * 4 + (s >> 5);   // 0..31
    const int b = bh >> 4;
    const int h = bh & 15;
    const int i0 = (s & 31) * 64;

    const int tid = threadIdx.x;
    const int w = tid >> 6;
    const int l = tid & 63;
    const int lrow = l & 15;
    const int lq = l >> 4;
    const int q0 = i0 + w * 16;

    const long baseBH = ((long)b * 2048) * 1024 + (long)h * 64;
    const long baseVT = (long)h * 64 * 4096 + (long)b * 2048;

    // Q fragments (A-layout: m=l&15, k=lq*8+j), hd=64 -> 2 frags
    const ushort_t* qrow = Q + baseBH + (long)(q0 + lrow) * 1024;
    bf16x8 aq0 = *(const bf16x8*)&qrow[lq * 8];
    bf16x8 aq1 = *(const bf16x8*)&qrow[32 + lq * 8];

    float lpart[4];
    f32x4 oacc[4];
#pragma unroll
    for (int r = 0; r < 4; r++) lpart[r] = 0.0f;
#pragma unroll
    for (int ni = 0; ni < 4; ni++) oacc[ni] = 0.0f;

    const int kstart = (i0 - 256) > 0 ? (i0 - 256) : 0;
    const int kend = i0 + 64;
    ushort_t* Pw = &Pb[w * 16 * 40];

    for (int cs = kstart; cs < kend; cs += 128) {
        const int ce = (cs + 128 < kend) ? cs + 128 : kend;
        // stage K chunk via swizzled global_load_lds, key index clamped
#pragma unroll
        for (int t = 0; t < 4; t++) {
            int idx = t * 256 + tid;
            int rr = idx >> 3;
            int cc = idx & 7;
            int c = cc ^ (rr & 7);
            int key = cs + rr;
            key = key < 2047 ? key : 2047;
            gload_lds16(&K[baseBH + (long)key * 1024 + c * 8], &Kl[idx * 8]);
        }
        // stage V^T chunk [64 d][128 keys]: 16 chunks of 8 keys per row,
        // XOR-swizzled (involution applied to global source chunk index)
#pragma unroll
        for (int t = 0; t < 4; t++) {
            int idx = t * 256 + tid;
            int rr = idx >> 4;               // d row 0..63
            int cc = idx & 15;               // lds chunk slot
            int c = (cc & 8) | ((cc & 7) ^ (rr & 7));
            int kc = cs + c * 8;             // chunk start key
            kc = kc < 2040 ? kc : 2040;      // clamp (masked keys, stay in-range)
            gload_lds16(&VT[baseVT + (long)rr * 4096 + kc], &Vtl[idx * 8]);
        }
        __syncthreads();

        for (int kb = cs; kb < ce; kb += 32) {
            if (kb > q0 + 15 || kb + 31 < q0 - 256) continue;  // fully masked
            const int rb = kb - cs;
            f32x4 S0 = 0.0f, S1 = 0.0f;
            {
                bf16x8 bk;
                bk = *(const bf16x8*)&Kl[sw(rb + lrow, lq)];
                S0 = __builtin_amdgcn_mfma_f32_16x16x32_bf16(aq0, bk, S0, 0, 0, 0);
                bk = *(const bf16x8*)&Kl[sw(rb + lrow, 4 + lq)];
                S0 = __builtin_amdgcn_mfma_f32_16x16x32_bf16(aq1, bk, S0, 0, 0, 0);
                bk = *(const bf16x8*)&Kl[sw(rb + 16 + lrow, lq)];
                S1 = __builtin_amdgcn_mfma_f32_16x16x32_bf16(aq0, bk, S1, 0, 0, 0);
                bk = *(const bf16x8*)&Kl[sw(rb + 16 + lrow, 4 + lq)];
                S1 = __builtin_amdgcn_mfma_f32_16x16x32_bf16(aq1, bk, S1, 0, 0, 0);
            }
            const int col0 = kb + lrow;
            const int col1 = kb + 16 + lrow;
#pragma unroll
            for (int r = 0; r < 4; r++) {
                const int i = q0 + lq * 4 + r;
                float p0 = (col0 > i || col0 < i - 256) ? 0.0f : exp2f(S0[r] * LOG2E);
                float p1 = (col1 > i || col1 < i - 256) ? 0.0f : exp2f(S1[r] * LOG2E);
                lpart[r] += p0 + p1;
                const int prow = lq * 4 + r;
                Pw[prow * 40 + lrow] = f2b(p0);
                Pw[prow * 40 + 16 + lrow] = f2b(p1);
            }
            // P: C-layout -> A-layout via LDS round-trip
            bf16x8 pf = *(const bf16x8*)&Pw[lrow * 40 + lq * 8];
            // V^T frag: row d = ni*16+lrow, keys rb+lq*8..+7 (swizzled chunk)
#pragma unroll
            for (int ni = 0; ni < 4; ni++) {
                int ccg = (rb >> 3) + lq;                       // global chunk 0..15
                int rsw = (ccg & 8) | ((ccg & 7) ^ (lrow & 7)); // row&7 == lrow&7
                bf16x8 vf = *(const bf16x8*)&Vtl[(ni * 16 + lrow) * 128 + rsw * 8];
                oacc[ni] = __builtin_amdgcn_mfma_f32_16x16x32_bf16(pf, vf, oacc[ni], 0, 0, 0);
            }
        }
        __syncthreads();
    }

    // deferred row-sum reduction (16-lane groups)
    float lS[4];
#pragma unroll
    for (int r = 0; r < 4; r++) {
        float rs = lpart[r];
#pragma unroll
        for (int off = 8; off; off >>= 1) rs += __shfl_xor(rs, off, 64);
        lS[r] = rs;
    }

#pragma unroll
    for (int ni = 0; ni < 4; ni++) {
#pragma unroll
        for (int r = 0; r < 4; r++) {
            const int i = q0 + lq * 4 + r;
            const int d = ni * 16 + lrow;
            O[baseBH + (long)i * 1024 + d] = f2b(oacc[ni][r] / lS[r]);
        }
    }
}

// ---------------------------------------------------------------------------
extern "C" void kernel_launch(void* const* d_in, const int* in_sizes, int n_in,
                              void* d_out, int out_size, void* d_ws, size_t ws_size,
                              hipStream_t stream) {
    const float* x  = (const float*)d_in[0];
    const float* Wq = (const float*)d_in[1];
    const float* bq = (const float*)d_in[2];
    const float* Wk = (const float*)d_in[3];
    const float* bk = (const float*)d_in[4];
    const float* Wv = (const float*)d_in[5];
    const float* bv = (const float*)d_in[6];
    const float* Wo = (const float*)d_in[7];
    const float* bo = (const float*)d_in[8];
    float* out = (float*)d_out;

    ushort_t* ws = (ushort_t*)d_ws;
    const size_t WMAT = (size_t)1024 * 1024;
    const size_t ACT = (size_t)2 * 2048 * 1024;
    ushort_t* xbf = ws;
    ushort_t* Wqt = xbf + ACT;
    ushort_t* Wkt = Wqt + WMAT;
    ushort_t* Wvt = Wkt + WMAT;
    ushort_t* Wot = Wvt + WMAT;
    ushort_t* qws = Wot + WMAT;
    ushort_t* kws = qws + ACT;
    ushort_t* vws = kws + ACT;      // holds VT[1024][4096]
    ushort_t* aws = xbf;  // attO aliases xbf (x dead after QKV)

    // 0+1) fused prep: x cast (z=4) + 4 weight transposes (z=0..3)
    prep_kernel<<<dim3(32, 32, 5), dim3(32, 8), 0, stream>>>(
        x, xbf, Wq, Wk, Wv, Wo, Wqt, Wkt, Wvt, Wot);

    // 2) fused QKV projection (Q pre-scaled 1/8; V stored transposed)
    gemm_qkv_kernel<<<1536, 256, 0, stream>>>(
        xbf, Wqt, Wkt, Wvt, bq, bk, bv, qws, kws, vws, 0.125f, 1.0f, 1.0f);

    // 3) windowed causal attention (V^T input)
    attn_kernel<<<1024, 256, 0, stream>>>(qws, kws, vws, aws);

    // 4) output projection
    gemm_out_kernel<<<512, 256, 0, stream>>>(aws, Wot, bo, out);
}

// Round 6
// 163.139 us; speedup vs baseline: 1.0019x; 1.0019x over previous
//
#include <hip/hip_runtime.h>

// Problem: B=2, N=2048, D=1024, H=16, hd=64, WINDOW=256 (causal + local window)
// Inputs FLOAT32, output FLOAT32; internal compute bf16 MFMA.
//
// R18: consolidation. (1) GEMMs reverted to R16 single-buffer structure —
// R17's 2-phase counted-vmcnt pipeline measured null (163.4 vs 163.1; also
// 6 vs 3 blocks/CU identical), confirming cross-block TLP already hides
// staging latency (m114). QKV declared at practical ceiling (~594 TF): any
// >=256-wide-tile schedule gives <=384 blocks -> 75% CU load-balance -> net 0.
// (2) prep W-transpose store phase widened: 1x ushort4 store/thread instead
// of 4x scalar 2B stores (4x fewer store instrs, same 64B coalescing).
// Attention unchanged from R16 (V pre-transposed, async-staged).

typedef unsigned short ushort_t;
typedef __bf16 bf16x8 __attribute__((ext_vector_type(8)));
typedef float f32x4 __attribute__((ext_vector_type(4)));
typedef unsigned short ushort8 __attribute__((ext_vector_type(8)));
typedef unsigned short ushort4v __attribute__((ext_vector_type(4)));

#define LOG2E 1.4426950408889634f

static __device__ __forceinline__ ushort_t f2b(float f) {
    union { float f; unsigned int u; } x;
    x.f = f;
    unsigned int u = x.u;
    unsigned int r = (u + 0x7FFFu + ((u >> 16) & 1u)) >> 16;
    return (ushort_t)r;
}

static __device__ __forceinline__ void store_out(float* p, float v) { *p = v; }
static __device__ __forceinline__ void store_out(ushort_t* p, float v) { *p = f2b(v); }

// swizzled element offset of 8-elem chunk c of row `row` (8 chunks/row)
static __device__ __forceinline__ int sw(int row, int c) {
    return (row * 8 + (c ^ (row & 7))) * 8;
}

// async global->LDS 16B copy: per-lane lds addr = wave-base + lane*16
static __device__ __forceinline__ void gload_lds16(const ushort_t* g, ushort_t* l) {
    __builtin_amdgcn_global_load_lds(
        (const __attribute__((address_space(1))) void*)g,
        (__attribute__((address_space(3))) void*)l, 16, 0, 0);
}

// ---------------------------------------------------------------------------
// 0+1) prep: z<4 -> 1024x1024 transpose+cast of W[z]; z==4 -> x cast (16/thr)
// Store phase: one ushort4 (8B) store per thread (was 4x scalar 2B).
// ---------------------------------------------------------------------------
__global__ __launch_bounds__(256) void prep_kernel(
    const float* __restrict__ x, ushort_t* __restrict__ xbf,
    const float* __restrict__ W0, const float* __restrict__ W1,
    const float* __restrict__ W2, const float* __restrict__ W3,
    ushort_t* __restrict__ T0, ushort_t* __restrict__ T1,
    ushort_t* __restrict__ T2, ushort_t* __restrict__ T3) {
    int tx = threadIdx.x, ty = threadIdx.y;  // block (32,8)
    if (blockIdx.z == 4) {
        // x cast: 1024 blocks x 256 threads x 16 elems = 4,194,304
        int idx = (blockIdx.y * 32 + blockIdx.x) * 256 + ty * 32 + tx;
        int i = idx * 16;
#pragma unroll
        for (int half = 0; half < 2; half++) {
            f32x4 a = *(const f32x4*)&x[i + half * 8];
            f32x4 b = *(const f32x4*)&x[i + half * 8 + 4];
            ushort8 o;
#pragma unroll
            for (int e = 0; e < 4; e++) o[e] = f2b(a[e]);
#pragma unroll
            for (int e = 0; e < 4; e++) o[4 + e] = f2b(b[e]);
            *(ushort8*)&xbf[i + half * 8] = o;
        }
        return;
    }
    __shared__ ushort_t tile[32][33];
    const float* W;
    ushort_t* T;
    switch (blockIdx.z) {
        case 0: W = W0; T = T0; break;
        case 1: W = W1; T = T1; break;
        case 2: W = W2; T = T2; break;
        default: W = W3; T = T3; break;
    }
    int xx = blockIdx.x * 32 + tx;
    int ybase = blockIdx.y * 32 + ty;
#pragma unroll
    for (int r = 0; r < 4; r++) tile[ty + r * 8][tx] = f2b(W[(ybase + r * 8) * 1024 + xx]);
    __syncthreads();
    // store: thread u covers out row ro=u>>3, cols cg..cg+3 (cg=(u&7)*4)
    {
        int u = ty * 32 + tx;
        int ro = u >> 3;             // 0..31 (output row = orig col)
        int cg = (u & 7) * 4;        // 0,4,..28 (output col group = orig row)
        ushort4v o;
#pragma unroll
        for (int k = 0; k < 4; k++) o[k] = tile[cg + k][ro];
        *(ushort4v*)&T[(long)(blockIdx.x * 32 + ro) * 1024 + blockIdx.y * 32 + cg] = o;
    }
}

// ---------------------------------------------------------------------------
// 2) QKV GEMM: C[M,1024] = (A @ Bt^T + bias) * oscale, 64x128 tile, 4 waves,
// global_load_lds staging with XOR-swizzled chunks, XCD swizzle, staggered K.
// 1536 blocks = 6/CU. zsel==2 (V) writes TRANSPOSED: VT[n][m], ushort4 packed.
// ---------------------------------------------------------------------------
__global__ __launch_bounds__(256) void gemm_qkv_kernel(
    const ushort_t* __restrict__ A,
    const ushort_t* __restrict__ Bt0, const ushort_t* __restrict__ Bt1,
    const ushort_t* __restrict__ Bt2,
    const float* __restrict__ bias0, const float* __restrict__ bias1,
    const float* __restrict__ bias2,
    ushort_t* __restrict__ C0, ushort_t* __restrict__ C1, ushort_t* __restrict__ C2,
    float os0, float os1, float os2) {
    __shared__ ushort_t Al[64 * 64];    // 8 KB
    __shared__ ushort_t Bl[128 * 64];   // 16 KB

    const int id = blockIdx.x;
    const int xcd = id & 7;
    const int s = id >> 3;
    int m_blk = (xcd >> 1) * 16 + (s & 15);       // 0..63
    int ncol = (xcd & 1) * 12 + (s >> 4);         // 0..23 fused (z,x)
    int zsel = ncol >> 3;
    ncol &= 7;
    const int m0 = m_blk * 64;
    const int n0 = ncol * 128;

    const ushort_t* Bt;
    const float* bias;
    ushort_t* C;
    float oscale;
    if (zsel == 0) { Bt = Bt0; bias = bias0; C = C0; oscale = os0; }
    else if (zsel == 1) { Bt = Bt1; bias = bias1; C = C1; oscale = os1; }
    else { Bt = Bt2; bias = bias2; C = C2; oscale = os2; }

    const int tid = threadIdx.x;
    const int w = tid >> 6;
    const int l = tid & 63;
    const int wm = (w >> 1) * 32;
    const int wn = (w & 1) * 64;
    const int lrow = l & 15;
    const int lq = l >> 4;

    f32x4 acc[2][4];
#pragma unroll
    for (int mi = 0; mi < 2; mi++)
#pragma unroll
        for (int ni = 0; ni < 4; ni++) acc[mi][ni] = 0.0f;

    const int kt0 = (id * 5) & 15;
    for (int it = 0; it < 16; it++) {
        const int kt = ((kt0 + it) & 15) * 64;
#pragma unroll
        for (int t = 0; t < 2; t++) {
            int idx = t * 256 + tid;
            int row = idx >> 3, cs = idx & 7, c = cs ^ (row & 7);
            gload_lds16(&A[(long)(m0 + row) * 1024 + kt + c * 8], &Al[idx * 8]);
        }
#pragma unroll
        for (int t = 0; t < 4; t++) {
            int idx = t * 256 + tid;
            int row = idx >> 3, cs = idx & 7, c = cs ^ (row & 7);
            gload_lds16(&Bt[(long)(n0 + row) * 1024 + kt + c * 8], &Bl[idx * 8]);
        }
        __syncthreads();
#pragma unroll
        for (int ks = 0; ks < 64; ks += 32) {
            const int cb = (ks >> 3) + lq;
            bf16x8 af[2], bfr[4];
#pragma unroll
            for (int mi = 0; mi < 2; mi++)
                af[mi] = *(const bf16x8*)&Al[sw(wm + mi * 16 + lrow, cb)];
#pragma unroll
            for (int ni = 0; ni < 4; ni++)
                bfr[ni] = *(const bf16x8*)&Bl[sw(wn + ni * 16 + lrow, cb)];
#pragma unroll
            for (int mi = 0; mi < 2; mi++)
#pragma unroll
                for (int ni = 0; ni < 4; ni++)
                    acc[mi][ni] = __builtin_amdgcn_mfma_f32_16x16x32_bf16(
                        af[mi], bfr[ni], acc[mi][ni], 0, 0, 0);
        }
        __syncthreads();
    }

    if (zsel == 2) {
        // V: transposed store VT[n][m], 4 consecutive m packed per lane (8B)
#pragma unroll
        for (int ni = 0; ni < 4; ni++) {
            int n = n0 + wn + ni * 16 + lrow;
            float bv = bias[n];
#pragma unroll
            for (int mi = 0; mi < 2; mi++) {
                int m = m0 + wm + mi * 16 + lq * 4;
                ushort4v o;
#pragma unroll
                for (int r = 0; r < 4; r++) o[r] = f2b((acc[mi][ni][r] + bv) * oscale);
                *(ushort4v*)&C[(long)n * 4096 + m] = o;
            }
        }
    } else {
#pragma unroll
        for (int ni = 0; ni < 4; ni++) {
            int n = n0 + wn + ni * 16 + lrow;
            float bv = bias[n];
#pragma unroll
            for (int mi = 0; mi < 2; mi++) {
#pragma unroll
                for (int r = 0; r < 4; r++) {
                    int m = m0 + wm + mi * 16 + lq * 4 + r;
                    store_out(&C[(long)m * 1024 + n], (acc[mi][ni][r] + bv) * oscale);
                }
            }
        }
    }
}

// ---------------------------------------------------------------------------
// 4) Out-proj GEMM: out[M,1024] = attO @ Wo^T + bo (fp32 out). 64x128 tile,
// XCD swizzle, staggered K, XOR-swizzled LDS chunks. 512 blocks.
// ---------------------------------------------------------------------------
__global__ __launch_bounds__(256) void gemm_out_kernel(
    const ushort_t* __restrict__ A, const ushort_t* __restrict__ Bt,
    const float* __restrict__ bias, float* __restrict__ C) {
    __shared__ ushort_t Al[64 * 64];
    __shared__ ushort_t Bl[128 * 64];

    const int id = blockIdx.x;
    const int xcd = id & 7;
    const int s = id >> 3;
    const int m_blk = xcd * 8 + (s & 7);          // 0..63
    const int ncol = s >> 3;                      // 0..7
    const int m0 = m_blk * 64;
    const int n0 = ncol * 128;

    const int tid = threadIdx.x;
    const int w = tid >> 6;
    const int l = tid & 63;
    const int wm = (w >> 1) * 32;
    const int wn = (w & 1) * 64;
    const int lrow = l & 15;
    const int lq = l >> 4;

    f32x4 acc[2][4];
#pragma unroll
    for (int mi = 0; mi < 2; mi++)
#pragma unroll
        for (int ni = 0; ni < 4; ni++) acc[mi][ni] = 0.0f;

    const int kt0 = (id * 5) & 15;
    for (int it = 0; it < 16; it++) {
        const int kt = ((kt0 + it) & 15) * 64;
#pragma unroll
        for (int t = 0; t < 2; t++) {
            int idx = t * 256 + tid;
            int row = idx >> 3, cs = idx & 7, c = cs ^ (row & 7);
            gload_lds16(&A[(long)(m0 + row) * 1024 + kt + c * 8], &Al[idx * 8]);
        }
#pragma unroll
        for (int t = 0; t < 4; t++) {
            int idx = t * 256 + tid;
            int row = idx >> 3, cs = idx & 7, c = cs ^ (row & 7);
            gload_lds16(&Bt[(long)(n0 + row) * 1024 + kt + c * 8], &Bl[idx * 8]);
        }
        __syncthreads();
#pragma unroll
        for (int ks = 0; ks < 64; ks += 32) {
            const int cb = (ks >> 3) + lq;
            bf16x8 af[2], bfr[4];
#pragma unroll
            for (int mi = 0; mi < 2; mi++)
                af[mi] = *(const bf16x8*)&Al[sw(wm + mi * 16 + lrow, cb)];
#pragma unroll
            for (int ni = 0; ni < 4; ni++)
                bfr[ni] = *(const bf16x8*)&Bl[sw(wn + ni * 16 + lrow, cb)];
#pragma unroll
            for (int mi = 0; mi < 2; mi++)
#pragma unroll
                for (int ni = 0; ni < 4; ni++)
                    acc[mi][ni] = __builtin_amdgcn_mfma_f32_16x16x32_bf16(
                        af[mi], bfr[ni], acc[mi][ni], 0, 0, 0);
        }
        __syncthreads();
    }

#pragma unroll
    for (int ni = 0; ni < 4; ni++) {
        int n = n0 + wn + ni * 16 + lrow;
        float bv = bias[n];
#pragma unroll
        for (int mi = 0; mi < 2; mi++) {
#pragma unroll
            for (int r = 0; r < 4; r++) {
                int m = m0 + wm + mi * 16 + lq * 4 + r;
                C[(long)m * 1024 + n] = acc[mi][ni][r] + bv;
            }
        }
    }
}

// ---------------------------------------------------------------------------
// 3) Flash attention, window=256 causal. 1024 blocks, XCD-swizzled. K tile
// AND V^T tile both staged via swizzled async gload_lds16 (no software
// transpose). VT input is [feature][token]. Fixed-max softmax, deferred
// row-sum, P round-trip via per-wave LDS buffer.
// ---------------------------------------------------------------------------
__global__ __launch_bounds__(256) void attn_kernel(
    const ushort_t* __restrict__ Q, const ushort_t* __restrict__ K,
    const ushort_t* __restrict__ VT, ushort_t* __restrict__ O) {
    __shared__ ushort_t Kl[128 * 64];    // K chunk, swizzled [key][d]     16 KB
    __shared__ ushort_t Vtl[64 * 128];   // V^T chunk, swizzled [d][key]   16 KB
    __shared__ ushort_t Pb[4 * 16 * 40]; // per-wave P buffer [16 q][32 key]

    const int id = blockIdx.x;
    const int xcd = id & 7;
    const int s = id >> 3;               // 0..127
    const int bh = xcd * 4 + (s >> 5);   // 0..31
    const int b = bh >> 4;
    const int h = bh & 15;
    const int i0 = (s & 31) * 64;

    const int tid = threadIdx.x;
    const int w = tid >> 6;
    const int l = tid & 63;
    const int lrow = l & 15;
    const int lq = l >> 4;
    const int q0 = i0 + w * 16;

    const long baseBH = ((long)b * 2048) * 1024 + (long)h * 64;
    const long baseVT = (long)h * 64 * 4096 + (long)b * 2048;

    // Q fragments (A-layout: m=l&15, k=lq*8+j), hd=64 -> 2 frags
    const ushort_t* qrow = Q + baseBH + (long)(q0 + lrow) * 1024;
    bf16x8 aq0 = *(const bf16x8*)&qrow[lq * 8];
    bf16x8 aq1 = *(const bf16x8*)&qrow[32 + lq * 8];

    float lpart[4];
    f32x4 oacc[4];
#pragma unroll
    for (int r = 0; r < 4; r++) lpart[r] = 0.0f;
#pragma unroll
    for (int ni = 0; ni < 4; ni++) oacc[ni] = 0.0f;

    const int kstart = (i0 - 256) > 0 ? (i0 - 256) : 0;
    const int kend = i0 + 64;
    ushort_t* Pw = &Pb[w * 16 * 40];

    for (int cs = kstart; cs < kend; cs += 128) {
        const int ce = (cs + 128 < kend) ? cs + 128 : kend;
        // stage K chunk via swizzled global_load_lds, key index clamped
#pragma unroll
        for (int t = 0; t < 4; t++) {
            int idx = t * 256 + tid;
            int rr = idx >> 3;
            int cc = idx & 7;
            int c = cc ^ (rr & 7);
            int key = cs + rr;
            key = key < 2047 ? key : 2047;
            gload_lds16(&K[baseBH + (long)key * 1024 + c * 8], &Kl[idx * 8]);
        }
        // stage V^T chunk [64 d][128 keys]: 16 chunks of 8 keys per row,
        // XOR-swizzled (involution applied to global source chunk index)
#pragma unroll
        for (int t = 0; t < 4; t++) {
            int idx = t * 256 + tid;
            int rr = idx >> 4;               // d row 0..63
            int cc = idx & 15;               // lds chunk slot
            int c = (cc & 8) | ((cc & 7) ^ (rr & 7));
            int kc = cs + c * 8;             // chunk start key
            kc = kc < 2040 ? kc : 2040;      // clamp (masked keys, stay in-range)
            gload_lds16(&VT[baseVT + (long)rr * 4096 + kc], &Vtl[idx * 8]);
        }
        __syncthreads();

        for (int kb = cs; kb < ce; kb += 32) {
            if (kb > q0 + 15 || kb + 31 < q0 - 256) continue;  // fully masked
            const int rb = kb - cs;
            f32x4 S0 = 0.0f, S1 = 0.0f;
            {
                bf16x8 bk;
                bk = *(const bf16x8*)&Kl[sw(rb + lrow, lq)];
                S0 = __builtin_amdgcn_mfma_f32_16x16x32_bf16(aq0, bk, S0, 0, 0, 0);
                bk = *(const bf16x8*)&Kl[sw(rb + lrow, 4 + lq)];
                S0 = __builtin_amdgcn_mfma_f32_16x16x32_bf16(aq1, bk, S0, 0, 0, 0);
                bk = *(const bf16x8*)&Kl[sw(rb + 16 + lrow, lq)];
                S1 = __builtin_amdgcn_mfma_f32_16x16x32_bf16(aq0, bk, S1, 0, 0, 0);
                bk = *(const bf16x8*)&Kl[sw(rb + 16 + lrow, 4 + lq)];
                S1 = __builtin_amdgcn_mfma_f32_16x16x32_bf16(aq1, bk, S1, 0, 0, 0);
            }
            const int col0 = kb + lrow;
            const int col1 = kb + 16 + lrow;
#pragma unroll
            for (int r = 0; r < 4; r++) {
                const int i = q0 + lq * 4 + r;
                float p0 = (col0 > i || col0 < i - 256) ? 0.0f : exp2f(S0[r] * LOG2E);
                float p1 = (col1 > i || col1 < i - 256) ? 0.0f : exp2f(S1[r] * LOG2E);
                lpart[r] += p0 + p1;
                const int prow = lq * 4 + r;
                Pw[prow * 40 + lrow] = f2b(p0);
                Pw[prow * 40 + 16 + lrow] = f2b(p1);
            }
            // P: C-layout -> A-layout via LDS round-trip
            bf16x8 pf = *(const bf16x8*)&Pw[lrow * 40 + lq * 8];
            // V^T frag: row d = ni*16+lrow, keys rb+lq*8..+7 (swizzled chunk)
#pragma unroll
            for (int ni = 0; ni < 4; ni++) {
                int ccg = (rb >> 3) + lq;                       // global chunk 0..15
                int rsw = (ccg & 8) | ((ccg & 7) ^ (lrow & 7)); // row&7 == lrow&7
                bf16x8 vf = *(const bf16x8*)&Vtl[(ni * 16 + lrow) * 128 + rsw * 8];
                oacc[ni] = __builtin_amdgcn_mfma_f32_16x16x32_bf16(pf, vf, oacc[ni], 0, 0, 0);
            }
        }
        __syncthreads();
    }

    // deferred row-sum reduction (16-lane groups)
    float lS[4];
#pragma unroll
    for (int r = 0; r < 4; r++) {
        float rs = lpart[r];
#pragma unroll
        for (int off = 8; off; off >>= 1) rs += __shfl_xor(rs, off, 64);
        lS[r] = rs;
    }

#pragma unroll
    for (int ni = 0; ni < 4; ni++) {
#pragma unroll
        for (int r = 0; r < 4; r++) {
            const int i = q0 + lq * 4 + r;
            const int d = ni * 16 + lrow;
            O[baseBH + (long)i * 1024 + d] = f2b(oacc[ni][r] / lS[r]);
        }
    }
}

// ---------------------------------------------------------------------------
extern "C" void kernel_launch(void* const* d_in, const int* in_sizes, int n_in,
                              void* d_out, int out_size, void* d_ws, size_t ws_size,
                              hipStream_t stream) {
    const float* x  = (const float*)d_in[0];
    const float* Wq = (const float*)d_in[1];
    const float* bq = (const float*)d_in[2];
    const float* Wk = (const float*)d_in[3];
    const float* bk = (const float*)d_in[4];
    const float* Wv = (const float*)d_in[5];
    const float* bv = (const float*)d_in[6];
    const float* Wo = (const float*)d_in[7];
    const float* bo = (const float*)d_in[8];
    float* out = (float*)d_out;

    ushort_t* ws = (ushort_t*)d_ws;
    const size_t WMAT = (size_t)1024 * 1024;
    const size_t ACT = (size_t)2 * 2048 * 1024;
    ushort_t* xbf = ws;
    ushort_t* Wqt = xbf + ACT;
    ushort_t* Wkt = Wqt + WMAT;
    ushort_t* Wvt = Wkt + WMAT;
    ushort_t* Wot = Wvt + WMAT;
    ushort_t* qws = Wot + WMAT;
    ushort_t* kws = qws + ACT;
    ushort_t* vws = kws + ACT;      // holds VT[1024][4096]
    ushort_t* aws = xbf;  // attO aliases xbf (x dead after QKV)

    // 0+1) fused prep: x cast (z=4) + 4 weight transposes (z=0..3)
    prep_kernel<<<dim3(32, 32, 5), dim3(32, 8), 0, stream>>>(
        x, xbf, Wq, Wk, Wv, Wo, Wqt, Wkt, Wvt, Wot);

    // 2) fused QKV projection (Q pre-scaled 1/8; V stored transposed)
    gemm_qkv_kernel<<<1536, 256, 0, stream>>>(
        xbf, Wqt, Wkt, Wvt, bq, bk, bv, qws, kws, vws, 0.125f, 1.0f, 1.0f);

    // 3) windowed causal attention (V^T input)
    attn_kernel<<<1024, 256, 0, stream>>>(qws, kws, vws, aws);

    // 4) output projection
    gemm_out_kernel<<<512, 256, 0, stream>>>(aws, Wot, bo, out);
}

// Round 7
// 161.326 us; speedup vs baseline: 1.0132x; 1.0112x over previous
//
#include <hip/hip_runtime.h>

// Problem: B=2, N=2048, D=1024, H=16, hd=64, WINDOW=256 (causal + local window)
// Inputs FLOAT32, output FLOAT32; internal compute bf16 MFMA.
//
// R19: attention inner-loop rotation (T15-minimum). Old per-kb chain:
// QK^T -> softmax -> P ds_write -> lgkm wait -> P ds_read -> PV  (LDS
// round-trip latency exposed every kb). New: PV of kb-1 runs between QK^T
// and softmax of kb (its P-writes are long retired -> no stall; PV MFMAs
// also hide QK^T latency). Same P buffer (read precedes write in program
// order), no extra LDS, occupancy unchanged. Plus wave-uniform interior/
// boundary mask split (kb,q0 uniform -> branch, not predication).
// GEMMs + prep frozen at R18.

typedef unsigned short ushort_t;
typedef __bf16 bf16x8 __attribute__((ext_vector_type(8)));
typedef float f32x4 __attribute__((ext_vector_type(4)));
typedef unsigned short ushort8 __attribute__((ext_vector_type(8)));
typedef unsigned short ushort4v __attribute__((ext_vector_type(4)));

#define LOG2E 1.4426950408889634f

static __device__ __forceinline__ ushort_t f2b(float f) {
    union { float f; unsigned int u; } x;
    x.f = f;
    unsigned int u = x.u;
    unsigned int r = (u + 0x7FFFu + ((u >> 16) & 1u)) >> 16;
    return (ushort_t)r;
}

static __device__ __forceinline__ void store_out(float* p, float v) { *p = v; }
static __device__ __forceinline__ void store_out(ushort_t* p, float v) { *p = f2b(v); }

// swizzled element offset of 8-elem chunk c of row `row` (8 chunks/row)
static __device__ __forceinline__ int sw(int row, int c) {
    return (row * 8 + (c ^ (row & 7))) * 8;
}

// async global->LDS 16B copy: per-lane lds addr = wave-base + lane*16
static __device__ __forceinline__ void gload_lds16(const ushort_t* g, ushort_t* l) {
    __builtin_amdgcn_global_load_lds(
        (const __attribute__((address_space(1))) void*)g,
        (__attribute__((address_space(3))) void*)l, 16, 0, 0);
}

// ---------------------------------------------------------------------------
// 0+1) prep: z<4 -> 1024x1024 transpose+cast of W[z]; z==4 -> x cast (16/thr)
// ---------------------------------------------------------------------------
__global__ __launch_bounds__(256) void prep_kernel(
    const float* __restrict__ x, ushort_t* __restrict__ xbf,
    const float* __restrict__ W0, const float* __restrict__ W1,
    const float* __restrict__ W2, const float* __restrict__ W3,
    ushort_t* __restrict__ T0, ushort_t* __restrict__ T1,
    ushort_t* __restrict__ T2, ushort_t* __restrict__ T3) {
    int tx = threadIdx.x, ty = threadIdx.y;  // block (32,8)
    if (blockIdx.z == 4) {
        // x cast: 1024 blocks x 256 threads x 16 elems = 4,194,304
        int idx = (blockIdx.y * 32 + blockIdx.x) * 256 + ty * 32 + tx;
        int i = idx * 16;
#pragma unroll
        for (int half = 0; half < 2; half++) {
            f32x4 a = *(const f32x4*)&x[i + half * 8];
            f32x4 b = *(const f32x4*)&x[i + half * 8 + 4];
            ushort8 o;
#pragma unroll
            for (int e = 0; e < 4; e++) o[e] = f2b(a[e]);
#pragma unroll
            for (int e = 0; e < 4; e++) o[4 + e] = f2b(b[e]);
            *(ushort8*)&xbf[i + half * 8] = o;
        }
        return;
    }
    __shared__ ushort_t tile[32][33];
    const float* W;
    ushort_t* T;
    switch (blockIdx.z) {
        case 0: W = W0; T = T0; break;
        case 1: W = W1; T = T1; break;
        case 2: W = W2; T = T2; break;
        default: W = W3; T = T3; break;
    }
    int xx = blockIdx.x * 32 + tx;
    int ybase = blockIdx.y * 32 + ty;
#pragma unroll
    for (int r = 0; r < 4; r++) tile[ty + r * 8][tx] = f2b(W[(ybase + r * 8) * 1024 + xx]);
    __syncthreads();
    // store: thread u covers out row ro=u>>3, cols cg..cg+3 (cg=(u&7)*4)
    {
        int u = ty * 32 + tx;
        int ro = u >> 3;             // 0..31 (output row = orig col)
        int cg = (u & 7) * 4;        // 0,4,..28 (output col group = orig row)
        ushort4v o;
#pragma unroll
        for (int k = 0; k < 4; k++) o[k] = tile[cg + k][ro];
        *(ushort4v*)&T[(long)(blockIdx.x * 32 + ro) * 1024 + blockIdx.y * 32 + cg] = o;
    }
}

// ---------------------------------------------------------------------------
// 2) QKV GEMM: C[M,1024] = (A @ Bt^T + bias) * oscale, 64x128 tile, 4 waves,
// global_load_lds staging with XOR-swizzled chunks, XCD swizzle, staggered K.
// 1536 blocks = 6/CU. zsel==2 (V) writes TRANSPOSED: VT[n][m], ushort4 packed.
// ---------------------------------------------------------------------------
__global__ __launch_bounds__(256) void gemm_qkv_kernel(
    const ushort_t* __restrict__ A,
    const ushort_t* __restrict__ Bt0, const ushort_t* __restrict__ Bt1,
    const ushort_t* __restrict__ Bt2,
    const float* __restrict__ bias0, const float* __restrict__ bias1,
    const float* __restrict__ bias2,
    ushort_t* __restrict__ C0, ushort_t* __restrict__ C1, ushort_t* __restrict__ C2,
    float os0, float os1, float os2) {
    __shared__ ushort_t Al[64 * 64];    // 8 KB
    __shared__ ushort_t Bl[128 * 64];   // 16 KB

    const int id = blockIdx.x;
    const int xcd = id & 7;
    const int s = id >> 3;
    int m_blk = (xcd >> 1) * 16 + (s & 15);       // 0..63
    int ncol = (xcd & 1) * 12 + (s >> 4);         // 0..23 fused (z,x)
    int zsel = ncol >> 3;
    ncol &= 7;
    const int m0 = m_blk * 64;
    const int n0 = ncol * 128;

    const ushort_t* Bt;
    const float* bias;
    ushort_t* C;
    float oscale;
    if (zsel == 0) { Bt = Bt0; bias = bias0; C = C0; oscale = os0; }
    else if (zsel == 1) { Bt = Bt1; bias = bias1; C = C1; oscale = os1; }
    else { Bt = Bt2; bias = bias2; C = C2; oscale = os2; }

    const int tid = threadIdx.x;
    const int w = tid >> 6;
    const int l = tid & 63;
    const int wm = (w >> 1) * 32;
    const int wn = (w & 1) * 64;
    const int lrow = l & 15;
    const int lq = l >> 4;

    f32x4 acc[2][4];
#pragma unroll
    for (int mi = 0; mi < 2; mi++)
#pragma unroll
        for (int ni = 0; ni < 4; ni++) acc[mi][ni] = 0.0f;

    const int kt0 = (id * 5) & 15;
    for (int it = 0; it < 16; it++) {
        const int kt = ((kt0 + it) & 15) * 64;
#pragma unroll
        for (int t = 0; t < 2; t++) {
            int idx = t * 256 + tid;
            int row = idx >> 3, cs = idx & 7, c = cs ^ (row & 7);
            gload_lds16(&A[(long)(m0 + row) * 1024 + kt + c * 8], &Al[idx * 8]);
        }
#pragma unroll
        for (int t = 0; t < 4; t++) {
            int idx = t * 256 + tid;
            int row = idx >> 3, cs = idx & 7, c = cs ^ (row & 7);
            gload_lds16(&Bt[(long)(n0 + row) * 1024 + kt + c * 8], &Bl[idx * 8]);
        }
        __syncthreads();
#pragma unroll
        for (int ks = 0; ks < 64; ks += 32) {
            const int cb = (ks >> 3) + lq;
            bf16x8 af[2], bfr[4];
#pragma unroll
            for (int mi = 0; mi < 2; mi++)
                af[mi] = *(const bf16x8*)&Al[sw(wm + mi * 16 + lrow, cb)];
#pragma unroll
            for (int ni = 0; ni < 4; ni++)
                bfr[ni] = *(const bf16x8*)&Bl[sw(wn + ni * 16 + lrow, cb)];
#pragma unroll
            for (int mi = 0; mi < 2; mi++)
#pragma unroll
                for (int ni = 0; ni < 4; ni++)
                    acc[mi][ni] = __builtin_amdgcn_mfma_f32_16x16x32_bf16(
                        af[mi], bfr[ni], acc[mi][ni], 0, 0, 0);
        }
        __syncthreads();
    }

    if (zsel == 2) {
        // V: transposed store VT[n][m], 4 consecutive m packed per lane (8B)
#pragma unroll
        for (int ni = 0; ni < 4; ni++) {
            int n = n0 + wn + ni * 16 + lrow;
            float bv = bias[n];
#pragma unroll
            for (int mi = 0; mi < 2; mi++) {
                int m = m0 + wm + mi * 16 + lq * 4;
                ushort4v o;
#pragma unroll
                for (int r = 0; r < 4; r++) o[r] = f2b((acc[mi][ni][r] + bv) * oscale);
                *(ushort4v*)&C[(long)n * 4096 + m] = o;
            }
        }
    } else {
#pragma unroll
        for (int ni = 0; ni < 4; ni++) {
            int n = n0 + wn + ni * 16 + lrow;
            float bv = bias[n];
#pragma unroll
            for (int mi = 0; mi < 2; mi++) {
#pragma unroll
                for (int r = 0; r < 4; r++) {
                    int m = m0 + wm + mi * 16 + lq * 4 + r;
                    store_out(&C[(long)m * 1024 + n], (acc[mi][ni][r] + bv) * oscale);
                }
            }
        }
    }
}

// ---------------------------------------------------------------------------
// 4) Out-proj GEMM: out[M,1024] = attO @ Wo^T + bo (fp32 out). 64x128 tile,
// XCD swizzle, staggered K, XOR-swizzled LDS chunks. 512 blocks.
// ---------------------------------------------------------------------------
__global__ __launch_bounds__(256) void gemm_out_kernel(
    const ushort_t* __restrict__ A, const ushort_t* __restrict__ Bt,
    const float* __restrict__ bias, float* __restrict__ C) {
    __shared__ ushort_t Al[64 * 64];
    __shared__ ushort_t Bl[128 * 64];

    const int id = blockIdx.x;
    const int xcd = id & 7;
    const int s = id >> 3;
    const int m_blk = xcd * 8 + (s & 7);          // 0..63
    const int ncol = s >> 3;                      // 0..7
    const int m0 = m_blk * 64;
    const int n0 = ncol * 128;

    const int tid = threadIdx.x;
    const int w = tid >> 6;
    const int l = tid & 63;
    const int wm = (w >> 1) * 32;
    const int wn = (w & 1) * 64;
    const int lrow = l & 15;
    const int lq = l >> 4;

    f32x4 acc[2][4];
#pragma unroll
    for (int mi = 0; mi < 2; mi++)
#pragma unroll
        for (int ni = 0; ni < 4; ni++) acc[mi][ni] = 0.0f;

    const int kt0 = (id * 5) & 15;
    for (int it = 0; it < 16; it++) {
        const int kt = ((kt0 + it) & 15) * 64;
#pragma unroll
        for (int t = 0; t < 2; t++) {
            int idx = t * 256 + tid;
            int row = idx >> 3, cs = idx & 7, c = cs ^ (row & 7);
            gload_lds16(&A[(long)(m0 + row) * 1024 + kt + c * 8], &Al[idx * 8]);
        }
#pragma unroll
        for (int t = 0; t < 4; t++) {
            int idx = t * 256 + tid;
            int row = idx >> 3, cs = idx & 7, c = cs ^ (row & 7);
            gload_lds16(&Bt[(long)(n0 + row) * 1024 + kt + c * 8], &Bl[idx * 8]);
        }
        __syncthreads();
#pragma unroll
        for (int ks = 0; ks < 64; ks += 32) {
            const int cb = (ks >> 3) + lq;
            bf16x8 af[2], bfr[4];
#pragma unroll
            for (int mi = 0; mi < 2; mi++)
                af[mi] = *(const bf16x8*)&Al[sw(wm + mi * 16 + lrow, cb)];
#pragma unroll
            for (int ni = 0; ni < 4; ni++)
                bfr[ni] = *(const bf16x8*)&Bl[sw(wn + ni * 16 + lrow, cb)];
#pragma unroll
            for (int mi = 0; mi < 2; mi++)
#pragma unroll
                for (int ni = 0; ni < 4; ni++)
                    acc[mi][ni] = __builtin_amdgcn_mfma_f32_16x16x32_bf16(
                        af[mi], bfr[ni], acc[mi][ni], 0, 0, 0);
        }
        __syncthreads();
    }

#pragma unroll
    for (int ni = 0; ni < 4; ni++) {
        int n = n0 + wn + ni * 16 + lrow;
        float bv = bias[n];
#pragma unroll
        for (int mi = 0; mi < 2; mi++) {
#pragma unroll
            for (int r = 0; r < 4; r++) {
                int m = m0 + wm + mi * 16 + lq * 4 + r;
                C[(long)m * 1024 + n] = acc[mi][ni][r] + bv;
            }
        }
    }
}

// ---------------------------------------------------------------------------
// 3) Flash attention, window=256 causal. 1024 blocks, XCD-swizzled. K tile
// AND V^T tile staged via swizzled async gload_lds16. R19: rotated inner
// loop (PV of kb-1 between QK^T and softmax of kb -> P LDS round-trip off
// the critical path) + wave-uniform interior (maskless) fast path.
// ---------------------------------------------------------------------------
__global__ __launch_bounds__(256) void attn_kernel(
    const ushort_t* __restrict__ Q, const ushort_t* __restrict__ K,
    const ushort_t* __restrict__ VT, ushort_t* __restrict__ O) {
    __shared__ ushort_t Kl[128 * 64];    // K chunk, swizzled [key][d]     16 KB
    __shared__ ushort_t Vtl[64 * 128];   // V^T chunk, swizzled [d][key]   16 KB
    __shared__ ushort_t Pb[4 * 16 * 40]; // per-wave P buffer [16 q][32 key]

    const int id = blockIdx.x;
    const int xcd = id & 7;
    const int s = id >> 3;               // 0..127
    const int bh = xcd * 4 + (s >> 5);   // 0..31
    const int b = bh >> 4;
    const int h = bh & 15;
    const int i0 = (s & 31) * 64;

    const int tid = threadIdx.x;
    const int w = tid >> 6;
    const int l = tid & 63;
    const int lrow = l & 15;
    const int lq = l >> 4;
    const int q0 = i0 + w * 16;

    const long baseBH = ((long)b * 2048) * 1024 + (long)h * 64;
    const long baseVT = (long)h * 64 * 4096 + (long)b * 2048;

    // Q fragments (A-layout: m=l&15, k=lq*8+j), hd=64 -> 2 frags
    const ushort_t* qrow = Q + baseBH + (long)(q0 + lrow) * 1024;
    bf16x8 aq0 = *(const bf16x8*)&qrow[lq * 8];
    bf16x8 aq1 = *(const bf16x8*)&qrow[32 + lq * 8];

    float lpart[4];
    f32x4 oacc[4];
#pragma unroll
    for (int r = 0; r < 4; r++) lpart[r] = 0.0f;
#pragma unroll
    for (int ni = 0; ni < 4; ni++) oacc[ni] = 0.0f;

    const int kstart = (i0 - 256) > 0 ? (i0 - 256) : 0;
    const int kend = i0 + 64;
    ushort_t* Pw = &Pb[w * 16 * 40];

    for (int cs = kstart; cs < kend; cs += 128) {
        const int ce = (cs + 128 < kend) ? cs + 128 : kend;
        // stage K chunk via swizzled global_load_lds, key index clamped
#pragma unroll
        for (int t = 0; t < 4; t++) {
            int idx = t * 256 + tid;
            int rr = idx >> 3;
            int cc = idx & 7;
            int c = cc ^ (rr & 7);
            int key = cs + rr;
            key = key < 2047 ? key : 2047;
            gload_lds16(&K[baseBH + (long)key * 1024 + c * 8], &Kl[idx * 8]);
        }
        // stage V^T chunk [64 d][128 keys]: 16 chunks of 8 keys per row,
        // XOR-swizzled (involution applied to global source chunk index)
#pragma unroll
        for (int t = 0; t < 4; t++) {
            int idx = t * 256 + tid;
            int rr = idx >> 4;               // d row 0..63
            int cc = idx & 15;               // lds chunk slot
            int c = (cc & 8) | ((cc & 7) ^ (rr & 7));
            int kc = cs + c * 8;             // chunk start key
            kc = kc < 2040 ? kc : 2040;      // clamp (masked keys, stay in-range)
            gload_lds16(&VT[baseVT + (long)rr * 4096 + kc], &Vtl[idx * 8]);
        }
        __syncthreads();

        int pend = -1;  // rb of the kb whose P is in Pw, PV not yet done
        for (int kb = cs; kb < ce; kb += 32) {
            if (kb > q0 + 15 || kb + 31 < q0 - 256) continue;  // fully masked
            const int rb = kb - cs;
            // 1) QK^T for current kb (issue first: longest latency)
            f32x4 S0 = 0.0f, S1 = 0.0f;
            {
                bf16x8 bk;
                bk = *(const bf16x8*)&Kl[sw(rb + lrow, lq)];
                S0 = __builtin_amdgcn_mfma_f32_16x16x32_bf16(aq0, bk, S0, 0, 0, 0);
                bk = *(const bf16x8*)&Kl[sw(rb + lrow, 4 + lq)];
                S0 = __builtin_amdgcn_mfma_f32_16x16x32_bf16(aq1, bk, S0, 0, 0, 0);
                bk = *(const bf16x8*)&Kl[sw(rb + 16 + lrow, lq)];
                S1 = __builtin_amdgcn_mfma_f32_16x16x32_bf16(aq0, bk, S1, 0, 0, 0);
                bk = *(const bf16x8*)&Kl[sw(rb + 16 + lrow, 4 + lq)];
                S1 = __builtin_amdgcn_mfma_f32_16x16x32_bf16(aq1, bk, S1, 0, 0, 0);
            }
            // 2) PV of the PREVIOUS kb (P writes long retired -> no lgkm stall;
            //    these MFMAs also hide the QK^T latency for step 3)
            if (pend >= 0) {
                bf16x8 pf = *(const bf16x8*)&Pw[lrow * 40 + lq * 8];
#pragma unroll
                for (int ni = 0; ni < 4; ni++) {
                    int ccg = (pend >> 3) + lq;
                    int rsw = (ccg & 8) | ((ccg & 7) ^ (lrow & 7));
                    bf16x8 vf = *(const bf16x8*)&Vtl[(ni * 16 + lrow) * 128 + rsw * 8];
                    oacc[ni] = __builtin_amdgcn_mfma_f32_16x16x32_bf16(pf, vf, oacc[ni], 0, 0, 0);
                }
            }
            // 3) softmax of current kb; interior blocks skip masks entirely
            //    (condition is wave-uniform: kb, q0 both uniform)
            if (kb <= q0 - 31 && kb >= q0 - 241) {
#pragma unroll
                for (int r = 0; r < 4; r++) {
                    float p0 = exp2f(S0[r] * LOG2E);
                    float p1 = exp2f(S1[r] * LOG2E);
                    lpart[r] += p0 + p1;
                    const int prow = lq * 4 + r;
                    Pw[prow * 40 + lrow] = f2b(p0);
                    Pw[prow * 40 + 16 + lrow] = f2b(p1);
                }
            } else {
                const int col0 = kb + lrow;
                const int col1 = kb + 16 + lrow;
#pragma unroll
                for (int r = 0; r < 4; r++) {
                    const int i = q0 + lq * 4 + r;
                    float p0 = (col0 > i || col0 < i - 256) ? 0.0f : exp2f(S0[r] * LOG2E);
                    float p1 = (col1 > i || col1 < i - 256) ? 0.0f : exp2f(S1[r] * LOG2E);
                    lpart[r] += p0 + p1;
                    const int prow = lq * 4 + r;
                    Pw[prow * 40 + lrow] = f2b(p0);
                    Pw[prow * 40 + 16 + lrow] = f2b(p1);
                }
            }
            pend = rb;
        }
        // drain pending PV before Vtl/Pw are invalidated by next chunk
        if (pend >= 0) {
            bf16x8 pf = *(const bf16x8*)&Pw[lrow * 40 + lq * 8];
#pragma unroll
            for (int ni = 0; ni < 4; ni++) {
                int ccg = (pend >> 3) + lq;
                int rsw = (ccg & 8) | ((ccg & 7) ^ (lrow & 7));
                bf16x8 vf = *(const bf16x8*)&Vtl[(ni * 16 + lrow) * 128 + rsw * 8];
                oacc[ni] = __builtin_amdgcn_mfma_f32_16x16x32_bf16(pf, vf, oacc[ni], 0, 0, 0);
            }
        }
        __syncthreads();
    }

    // deferred row-sum reduction (16-lane groups)
    float lS[4];
#pragma unroll
    for (int r = 0; r < 4; r++) {
        float rs = lpart[r];
#pragma unroll
        for (int off = 8; off; off >>= 1) rs += __shfl_xor(rs, off, 64);
        lS[r] = rs;
    }

#pragma unroll
    for (int ni = 0; ni < 4; ni++) {
#pragma unroll
        for (int r = 0; r < 4; r++) {
            const int i = q0 + lq * 4 + r;
            const int d = ni * 16 + lrow;
            O[baseBH + (long)i * 1024 + d] = f2b(oacc[ni][r] / lS[r]);
        }
    }
}

// ---------------------------------------------------------------------------
extern "C" void kernel_launch(void* const* d_in, const int* in_sizes, int n_in,
                              void* d_out, int out_size, void* d_ws, size_t ws_size,
                              hipStream_t stream) {
    const float* x  = (const float*)d_in[0];
    const float* Wq = (const float*)d_in[1];
    const float* bq = (const float*)d_in[2];
    const float* Wk = (const float*)d_in[3];
    const float* bk = (const float*)d_in[4];
    const float* Wv = (const float*)d_in[5];
    const float* bv = (const float*)d_in[6];
    const float* Wo = (const float*)d_in[7];
    const float* bo = (const float*)d_in[8];
    float* out = (float*)d_out;

    ushort_t* ws = (ushort_t*)d_ws;
    const size_t WMAT = (size_t)1024 * 1024;
    const size_t ACT = (size_t)2 * 2048 * 1024;
    ushort_t* xbf = ws;
    ushort_t* Wqt = xbf + ACT;
    ushort_t* Wkt = Wqt + WMAT;
    ushort_t* Wvt = Wkt + WMAT;
    ushort_t* Wot = Wvt + WMAT;
    ushort_t* qws = Wot + WMAT;
    ushort_t* kws = qws + ACT;
    ushort_t* vws = kws + ACT;      // holds VT[1024][4096]
    ushort_t* aws = xbf;  // attO aliases xbf (x dead after QKV)

    // 0+1) fused prep: x cast (z=4) + 4 weight transposes (z=0..3)
    prep_kernel<<<dim3(32, 32, 5), dim3(32, 8), 0, stream>>>(
        x, xbf, Wq, Wk, Wv, Wo, Wqt, Wkt, Wvt, Wot);

    // 2) fused QKV projection (Q pre-scaled 1/8; V stored transposed)
    gemm_qkv_kernel<<<1536, 256, 0, stream>>>(
        xbf, Wqt, Wkt, Wvt, bq, bk, bv, qws, kws, vws, 0.125f, 1.0f, 1.0f);

    // 3) windowed causal attention (V^T input)
    attn_kernel<<<1024, 256, 0, stream>>>(qws, kws, vws, aws);

    // 4) output projection
    gemm_out_kernel<<<512, 256, 0, stream>>>(aws, Wot, bo, out);
}